// Round 4
// baseline (254453.223 us; speedup 1.0000x reference)
//
#include <hip/hip_runtime.h>
#include <hip/hip_fp16.h>
#include <hip/hip_cooperative_groups.h>

#define N 4096
#define L 4096
#define NPART 32   // i-chunks (rows 128 each)
#define NJB 16     // j-blocks (cols 256 each)
#define CPB 256    // cols per block
#define RPB 128    // rows per block

// ---------- init: zero d_out, seed partial buffer with state_dist ----------
__global__ __launch_bounds__(256) void init_kernel(const float* __restrict__ sd,
                                                   float* __restrict__ vwpart,
                                                   float* __restrict__ out) {
    int g = blockIdx.x * 256 + threadIdx.x;          // grid 512 -> 131072 threads
    if (g < L * 4) out[g] = 0.0f;
    if (g < NPART * N) vwpart[g] = (g < N) ? sd[g] : 0.0f;  // partial 0 = sd, rest 0
}

// ---------- robust symbol decode: handles int32 OR int64 device layout ----------
__global__ __launch_bounds__(256) void decode_seq_kernel(const int* __restrict__ seq32,
                                                         unsigned char* __restrict__ syms) {
    __shared__ int any_odd;
    if (threadIdx.x == 0) any_odd = 0;
    __syncthreads();
    int acc = 0;
    for (int i = threadIdx.x; i < L / 2; i += 256) acc |= seq32[2 * i + 1];
    if (acc) any_odd = 1;
    __syncthreads();
    const int is64 = (any_odd == 0);
    for (int t = threadIdx.x; t < L; t += 256) {
        int v = is64 ? seq32[2 * t] : seq32[t];
        syms[t] = (unsigned char)(v & 1);
    }
}

// ---------- softmax over T rows -> fp16 Tm[s][i][j] + row-mass correction ----------
// rowc[s][i] = 1 / sum_j fp16(softmax_row)[j]  (fp32 sum of the QUANTIZED values)
// => corrected matrix rowc[i]*q[i][j] is exactly row-stochastic.
__global__ __launch_bounds__(256) void softmax_T_kernel(const float* __restrict__ T,
                                                        unsigned short* __restrict__ Tm,
                                                        float* __restrict__ rowc) {
    int row = blockIdx.x;              // 0..8191 == i*2 + s
    int i = row >> 1, s = row & 1;
    const float* src = T + (size_t)row * N;
    unsigned short* dst = Tm + ((size_t)s << 24) + ((size_t)i << 12);
    int tid = threadIdx.x;

    float vals[16];
    float mx = -1e30f;
#pragma unroll
    for (int k = 0; k < 16; k++) {
        vals[k] = src[tid + (k << 8)];
        mx = fmaxf(mx, vals[k]);
    }
#pragma unroll
    for (int o = 32; o > 0; o >>= 1) mx = fmaxf(mx, __shfl_xor(mx, o));
    __shared__ float red[4];
    int wid = tid >> 6;
    if ((tid & 63) == 0) red[wid] = mx;
    __syncthreads();
    mx = fmaxf(fmaxf(red[0], red[1]), fmaxf(red[2], red[3]));
    __syncthreads();

    float sum = 0.0f;
#pragma unroll
    for (int k = 0; k < 16; k++) {
        vals[k] = __expf(vals[k] - mx);
        sum += vals[k];
    }
#pragma unroll
    for (int o = 32; o > 0; o >>= 1) sum += __shfl_xor(sum, o);
    if ((tid & 63) == 0) red[wid] = sum;
    __syncthreads();
    sum = red[0] + red[1] + red[2] + red[3];
    __syncthreads();
    float inv = 1.0f / sum;

    // quantize to fp16, and accumulate the exact fp32 sum of quantized values
    float qs = 0.0f;
#pragma unroll
    for (int k = 0; k < 16; k++) {
        __half h = __float2half_rn(vals[k] * inv);
        dst[tid + (k << 8)] = __half_as_ushort(h);
        qs += __half2float(h);
    }
#pragma unroll
    for (int o = 32; o > 0; o >>= 1) qs += __shfl_xor(qs, o);
    if ((tid & 63) == 0) red[wid] = qs;
    __syncthreads();
    if (tid == 0) {
        float q = red[0] + red[1] + red[2] + red[3];
        rowc[(size_t)s * N + i] = 1.0f / q;
    }
}

// ---------- softmax over O rows (4 wide) -> fp32 Om[s][i][c] ----------
__global__ __launch_bounds__(256) void softmax_O_kernel(const float* __restrict__ O,
                                                        float* __restrict__ Om) {
    int r = blockIdx.x * 256 + threadIdx.x;        // 0..8191 == i*2 + s
    if (r < 2 * N) {
        float4 x = *(const float4*)(O + (size_t)r * 4);
        float mx = fmaxf(fmaxf(x.x, x.y), fmaxf(x.z, x.w));
        float e0 = __expf(x.x - mx), e1 = __expf(x.y - mx);
        float e2 = __expf(x.z - mx), e3 = __expf(x.w - mx);
        float inv = 1.0f / (e0 + e1 + e2 + e3);
        int i = r >> 1, s = r & 1;
        *(float4*)(Om + (size_t)s * (N * 4) + (size_t)i * 4) =
            make_float4(e0 * inv, e1 * inv, e2 * inv, e3 * inv);
    }
}

// ---------- persistent scan kernel (cooperative) ----------
// 512 blocks x 256 threads. jb = blockIdx & 15 (256 cols), ic = blockIdx >> 4 (128 rows).
// Step t: reduce vwpart[t&1] rows -> v,vc (LDS; vc = row-mass-corrected); partial
// matvec over fp16 Tm into LDS colacc; write exclusive slice of vwpart[(t+1)&1];
// jb==0 blocks project out[t] from the RAW state v.
__global__ __launch_bounds__(256, 2) void scan_kernel(const unsigned short* __restrict__ Tm,
                                                      const float* __restrict__ rowc,
                                                      const float* __restrict__ Om,
                                                      const unsigned char* __restrict__ syms,
                                                      float* __restrict__ vwpart,
                                                      float* __restrict__ out) {
    cooperative_groups::grid_group grid = cooperative_groups::this_grid();
    const int tid = threadIdx.x;
    const int jb = blockIdx.x & 15;
    const int ic = blockIdx.x >> 4;      // 0..31
    const int i0 = ic * RPB;
    const int j0 = jb * CPB;

    __shared__ float v[RPB];      // raw state rows
    __shared__ float vc[RPB];     // row-mass-corrected state rows
    __shared__ float colacc[CPB];
    __shared__ float oacc[4];

    const int cg = tid & 31;             // col group: 8 cols each
    const int rg = tid >> 5;             // row group: 8 groups x 16 rows

    for (int t = 0; t < L; t++) {
        const int s = syms[t];
        const float* vin = vwpart + (size_t)(t & 1) * (NPART * N);
        float*       vout = vwpart + (size_t)((t + 1) & 1) * (NPART * N);

        // stage v rows: sum the 32 partials for this block's 128 rows
        if (tid < RPB) {
            float accv = 0.0f;
#pragma unroll
            for (int p = 0; p < NPART; p++) accv += vin[p * N + i0 + tid];
            v[tid] = accv;
            vc[tid] = accv * rowc[(size_t)s * N + i0 + tid];
        }
        colacc[tid] = 0.0f;
        if (tid < 4) oacc[tid] = 0.0f;
        __syncthreads();

        // partial matvec: rows [i0+rg*16, +16), cols [j0+cg*8, +8)
        const unsigned short* base =
            Tm + ((size_t)s << 24) + (size_t)(i0 + rg * 16) * N + (j0 + cg * 8);
        float a[8];
#pragma unroll
        for (int e = 0; e < 8; e++) a[e] = 0.0f;
#pragma unroll
        for (int r = 0; r < 16; r++) {
            uint4 w = *(const uint4*)(base + (size_t)r * N);
            float vi = vc[rg * 16 + r];
            float2 f0 = __half22float2(*(__half2*)&w.x);
            float2 f1 = __half22float2(*(__half2*)&w.y);
            float2 f2 = __half22float2(*(__half2*)&w.z);
            float2 f3 = __half22float2(*(__half2*)&w.w);
            a[0] += vi * f0.x; a[1] += vi * f0.y;
            a[2] += vi * f1.x; a[3] += vi * f1.y;
            a[4] += vi * f2.x; a[5] += vi * f2.y;
            a[6] += vi * f3.x; a[7] += vi * f3.y;
        }
#pragma unroll
        for (int e = 0; e < 8; e++) atomicAdd(&colacc[cg * 8 + e], a[e]);

        // fused output projection partials (32 jb==0 blocks) — uses RAW state v
        if (jb == 0) {
            int r = tid >> 2, c = tid & 3;   // r in [0,64)
            float p = v[r] * Om[((size_t)s * N + (i0 + r)) * 4 + c]
                    + v[r + 64] * Om[((size_t)s * N + (i0 + r + 64)) * 4 + c];
            p += __shfl_down(p, 32);
            p += __shfl_down(p, 16);
            p += __shfl_down(p, 8);
            p += __shfl_down(p, 4);
            if ((tid & 63) < 4) atomicAdd(&oacc[c], p);
        }
        __syncthreads();

        // write this block's exclusive partial slice (coalesced float4)
        if (tid < 64) {
            float4 val = *(float4*)&colacc[tid * 4];
            *(float4*)&vout[(size_t)ic * N + j0 + tid * 4] = val;
        }
        if (jb == 0 && tid < 4) atomicAdd(&out[t * 4 + tid], oacc[tid]);

        grid.sync();
    }
}

extern "C" void kernel_launch(void* const* d_in, const int* in_sizes, int n_in,
                              void* d_out, int out_size, void* d_ws, size_t ws_size,
                              hipStream_t stream) {
    const float* sd  = (const float*)d_in[0];   // [4096]
    const int*   seq = (const int*)d_in[1];     // [4096]
    const float* T   = (const float*)d_in[2];   // [4096,2,4096]
    const float* O   = (const float*)d_in[3];   // [4096,2,4]
    float* out = (float*)d_out;                 // [4096,4]

    const size_t TM_BYTES  = (size_t)2 * N * N * 2;          // 64 MiB fp16
    const size_t RC_BYTES  = (size_t)2 * N * 4;              // 32 KiB
    const size_t OM_BYTES  = 2 * N * 4 * sizeof(float);      // 128 KiB
    const size_t VW_BYTES  = (size_t)2 * NPART * N * 4;      // 1 MiB

    char* ws = (char*)d_ws;
    unsigned short* Tm = (unsigned short*)ws;
    float* rowc   = (float*)(ws + TM_BYTES);
    float* Om     = (float*)(ws + TM_BYTES + RC_BYTES);
    float* vwpart = (float*)(ws + TM_BYTES + RC_BYTES + OM_BYTES);
    unsigned char* syms = (unsigned char*)(ws + TM_BYTES + RC_BYTES + OM_BYTES + VW_BYTES);

    hipLaunchKernelGGL(init_kernel, dim3(512), dim3(256), 0, stream, sd, vwpart, out);
    hipLaunchKernelGGL(decode_seq_kernel, dim3(1), dim3(256), 0, stream, seq, syms);
    hipLaunchKernelGGL(softmax_T_kernel, dim3(2 * N), dim3(256), 0, stream, T, Tm, rowc);
    hipLaunchKernelGGL(softmax_O_kernel, dim3(32), dim3(256), 0, stream, O, Om);

    void* args[] = { (void*)&Tm, (void*)&rowc, (void*)&Om, (void*)&syms,
                     (void*)&vwpart, (void*)&out };
    hipLaunchCooperativeKernel((const void*)scan_kernel, dim3(NJB * NPART), dim3(256),
                               args, 0, stream);
}

// Round 5
// 41242.929 us; speedup vs baseline: 6.1696x; 6.1696x over previous
//
#include <hip/hip_runtime.h>
#include <hip/hip_fp16.h>

#define N 4096
#define L 4096
#define NPART 32   // i-chunks (rows 128 each)
#define NJB 16     // j-blocks (cols 256 each)
#define CPB 256    // cols per block
#define RPB 128    // rows per block

#define AS(p, v) __hip_atomic_store((p), (v), __ATOMIC_RELAXED, __HIP_MEMORY_SCOPE_AGENT)
#define AL(p)    __hip_atomic_load((p), __ATOMIC_RELAXED, __HIP_MEMORY_SCOPE_AGENT)

// ---------- init: zero d_out, seed triple partial buffer, zero ready counters ----------
__global__ __launch_bounds__(256) void init_kernel(const float* __restrict__ sd,
                                                   float* __restrict__ vwpart,
                                                   unsigned* __restrict__ ready,
                                                   float* __restrict__ out) {
    int g = blockIdx.x * 256 + threadIdx.x;          // grid 1536 -> 393216 threads
    if (g < L * 4) out[g] = 0.0f;
    if (g < 3 * NPART * N) AS(&vwpart[g], (g < N) ? sd[g] : 0.0f);  // buf0 part0 = sd
    if (g < NJB * 64) AS(&ready[g], 0u);
}

// ---------- robust symbol decode: handles int32 OR int64 device layout ----------
__global__ __launch_bounds__(256) void decode_seq_kernel(const int* __restrict__ seq32,
                                                         unsigned char* __restrict__ syms) {
    __shared__ int any_odd;
    if (threadIdx.x == 0) any_odd = 0;
    __syncthreads();
    int acc = 0;
    for (int i = threadIdx.x; i < L / 2; i += 256) acc |= seq32[2 * i + 1];
    if (acc) any_odd = 1;
    __syncthreads();
    const int is64 = (any_odd == 0);
    for (int t = threadIdx.x; t < L; t += 256) {
        int v = is64 ? seq32[2 * t] : seq32[t];
        syms[t] = (unsigned char)(v & 1);
    }
}

// ---------- softmax over T rows -> fp16 Tm[s][i][j] + row-mass correction ----------
// rowc[s][i] = 1 / sum_j fp16(softmax_row)[j]  => corrected matrix exactly row-stochastic.
__global__ __launch_bounds__(256) void softmax_T_kernel(const float* __restrict__ T,
                                                        unsigned short* __restrict__ Tm,
                                                        float* __restrict__ rowc) {
    int row = blockIdx.x;              // 0..8191 == i*2 + s
    int i = row >> 1, s = row & 1;
    const float* src = T + (size_t)row * N;
    unsigned short* dst = Tm + ((size_t)s << 24) + ((size_t)i << 12);
    int tid = threadIdx.x;

    float vals[16];
    float mx = -1e30f;
#pragma unroll
    for (int k = 0; k < 16; k++) {
        vals[k] = src[tid + (k << 8)];
        mx = fmaxf(mx, vals[k]);
    }
#pragma unroll
    for (int o = 32; o > 0; o >>= 1) mx = fmaxf(mx, __shfl_xor(mx, o));
    __shared__ float red[4];
    int wid = tid >> 6;
    if ((tid & 63) == 0) red[wid] = mx;
    __syncthreads();
    mx = fmaxf(fmaxf(red[0], red[1]), fmaxf(red[2], red[3]));
    __syncthreads();

    float sum = 0.0f;
#pragma unroll
    for (int k = 0; k < 16; k++) {
        vals[k] = __expf(vals[k] - mx);
        sum += vals[k];
    }
#pragma unroll
    for (int o = 32; o > 0; o >>= 1) sum += __shfl_xor(sum, o);
    if ((tid & 63) == 0) red[wid] = sum;
    __syncthreads();
    sum = red[0] + red[1] + red[2] + red[3];
    __syncthreads();
    float inv = 1.0f / sum;

    float qs = 0.0f;
#pragma unroll
    for (int k = 0; k < 16; k++) {
        __half h = __float2half_rn(vals[k] * inv);
        dst[tid + (k << 8)] = __half_as_ushort(h);
        qs += __half2float(h);
    }
#pragma unroll
    for (int o = 32; o > 0; o >>= 1) qs += __shfl_xor(qs, o);
    if ((tid & 63) == 0) red[wid] = qs;
    __syncthreads();
    if (tid == 0) {
        float q = red[0] + red[1] + red[2] + red[3];
        rowc[(size_t)s * N + i] = 1.0f / q;
    }
}

// ---------- softmax over O rows (4 wide) -> fp32 Om[s][i][c] ----------
__global__ __launch_bounds__(256) void softmax_O_kernel(const float* __restrict__ O,
                                                        float* __restrict__ Om) {
    int r = blockIdx.x * 256 + threadIdx.x;        // 0..8191 == i*2 + s
    if (r < 2 * N) {
        float4 x = *(const float4*)(O + (size_t)r * 4);
        float mx = fmaxf(fmaxf(x.x, x.y), fmaxf(x.z, x.w));
        float e0 = __expf(x.x - mx), e1 = __expf(x.y - mx);
        float e2 = __expf(x.z - mx), e3 = __expf(x.w - mx);
        float inv = 1.0f / (e0 + e1 + e2 + e3);
        int i = r >> 1, s = r & 1;
        *(float4*)(Om + (size_t)s * (N * 4) + (size_t)i * 4) =
            make_float4(e0 * inv, e1 * inv, e2 * inv, e3 * inv);
    }
}

// ---------- persistent scan kernel with point-to-point sync ----------
// 512 blocks x 256 threads, cooperative (co-residency only; NO grid.sync).
// Triple-buffered partials; consumer (ic,jb) waits on ready[ic>>1] >= 32*t;
// producer (ic,jb) bumps ready[jb] after writing its slice.
// All vwpart / ready traffic is agent-scope (MALL) -> Tm stays hot in L2.
__global__ __launch_bounds__(256, 2) void scan_kernel(const unsigned short* __restrict__ Tm,
                                                      const float* __restrict__ rowc,
                                                      const float* __restrict__ Om,
                                                      const unsigned char* __restrict__ syms,
                                                      float* __restrict__ vwpart,
                                                      unsigned* __restrict__ ready,
                                                      float* __restrict__ out) {
    const int tid = threadIdx.x;
    const int jb = blockIdx.x & 15;
    const int ic = blockIdx.x >> 4;      // 0..31
    const int i0 = ic * RPB;
    const int j0 = jb * CPB;

    __shared__ float v[RPB];      // raw state rows
    __shared__ float vc[RPB];     // row-mass-corrected state rows
    __shared__ float colacc[CPB];
    __shared__ float oacc[4];

    const int cg = tid & 31;             // col group: 8 cols each
    const int rg = tid >> 5;             // row group: 8 groups x 16 rows

    unsigned* wait_ctr = &ready[(ic >> 1) * 64];
    unsigned* bump_ctr = &ready[jb * 64];

    for (int t = 0; t < L; t++) {
        const int s = syms[t];
        const float* vin  = vwpart + (size_t)(t % 3) * (NPART * N);
        float*       vout = vwpart + (size_t)((t + 1) % 3) * (NPART * N);

        // ---- wait for this step's input partials (monotone counter) ----
        if (tid == 0) {
            unsigned target = 32u * (unsigned)t;
            while (AL(wait_ctr) < target) __builtin_amdgcn_s_sleep(1);
        }
        __syncthreads();

        // ---- stage v rows: sum the 32 partials for this block's 128 rows ----
        if (tid < RPB) {
            float accv = 0.0f;
#pragma unroll
            for (int p = 0; p < NPART; p++) accv += AL(&vin[p * N + i0 + tid]);
            v[tid] = accv;
            vc[tid] = accv * rowc[(size_t)s * N + i0 + tid];
        }
        colacc[tid] = 0.0f;
        if (tid < 4) oacc[tid] = 0.0f;
        __syncthreads();

        // ---- partial matvec: rows [i0+rg*16,+16), cols [j0+cg*8,+8) ----
        const unsigned short* base =
            Tm + ((size_t)s << 24) + (size_t)(i0 + rg * 16) * N + (j0 + cg * 8);
        float a[8];
#pragma unroll
        for (int e = 0; e < 8; e++) a[e] = 0.0f;
#pragma unroll
        for (int r = 0; r < 16; r++) {
            uint4 w = *(const uint4*)(base + (size_t)r * N);
            float vi = vc[rg * 16 + r];
            float2 f0 = __half22float2(*(__half2*)&w.x);
            float2 f1 = __half22float2(*(__half2*)&w.y);
            float2 f2 = __half22float2(*(__half2*)&w.z);
            float2 f3 = __half22float2(*(__half2*)&w.w);
            a[0] += vi * f0.x; a[1] += vi * f0.y;
            a[2] += vi * f1.x; a[3] += vi * f1.y;
            a[4] += vi * f2.x; a[5] += vi * f2.y;
            a[6] += vi * f3.x; a[7] += vi * f3.y;
        }
#pragma unroll
        for (int e = 0; e < 8; e++) atomicAdd(&colacc[cg * 8 + e], a[e]);

        // ---- fused output projection partials (jb==0 blocks) — RAW state v ----
        if (jb == 0) {
            int r = tid >> 2, c = tid & 3;   // r in [0,64)
            float p = v[r] * Om[((size_t)s * N + (i0 + r)) * 4 + c]
                    + v[r + 64] * Om[((size_t)s * N + (i0 + r + 64)) * 4 + c];
            p += __shfl_down(p, 32);
            p += __shfl_down(p, 16);
            p += __shfl_down(p, 8);
            p += __shfl_down(p, 4);
            if ((tid & 63) < 4) atomicAdd(&oacc[c], p);
        }
        __syncthreads();

        // ---- publish this block's exclusive partial slice (agent-scope) ----
        AS(&vout[(size_t)ic * N + j0 + tid], colacc[tid]);
        if (jb == 0 && tid < 4) atomicAdd(&out[t * 4 + tid], oacc[tid]);
        __syncthreads();   // drains vmcnt(0) -> slice visible at MALL

        if (tid == 0) {
            __hip_atomic_fetch_add(bump_ctr, 1u, __ATOMIC_RELAXED,
                                   __HIP_MEMORY_SCOPE_AGENT);
        }
    }
}

extern "C" void kernel_launch(void* const* d_in, const int* in_sizes, int n_in,
                              void* d_out, int out_size, void* d_ws, size_t ws_size,
                              hipStream_t stream) {
    const float* sd  = (const float*)d_in[0];   // [4096]
    const int*   seq = (const int*)d_in[1];     // [4096]
    const float* T   = (const float*)d_in[2];   // [4096,2,4096]
    const float* O   = (const float*)d_in[3];   // [4096,2,4]
    float* out = (float*)d_out;                 // [4096,4]

    const size_t TM_BYTES  = (size_t)2 * N * N * 2;          // 64 MiB fp16
    const size_t RC_BYTES  = (size_t)2 * N * 4;              // 32 KiB
    const size_t OM_BYTES  = 2 * N * 4 * sizeof(float);      // 128 KiB
    const size_t VW_BYTES  = (size_t)3 * NPART * N * 4;      // 1.5 MiB
    const size_t RD_BYTES  = (size_t)NJB * 64 * 4;           // 4 KiB padded counters

    char* ws = (char*)d_ws;
    unsigned short* Tm = (unsigned short*)ws;
    float* rowc   = (float*)(ws + TM_BYTES);
    float* Om     = (float*)(ws + TM_BYTES + RC_BYTES);
    float* vwpart = (float*)(ws + TM_BYTES + RC_BYTES + OM_BYTES);
    unsigned* ready = (unsigned*)(ws + TM_BYTES + RC_BYTES + OM_BYTES + VW_BYTES);
    unsigned char* syms = (unsigned char*)(ws + TM_BYTES + RC_BYTES + OM_BYTES + VW_BYTES + RD_BYTES);

    hipLaunchKernelGGL(init_kernel, dim3(1536), dim3(256), 0, stream, sd, vwpart, ready, out);
    hipLaunchKernelGGL(decode_seq_kernel, dim3(1), dim3(256), 0, stream, seq, syms);
    hipLaunchKernelGGL(softmax_T_kernel, dim3(2 * N), dim3(256), 0, stream, T, Tm, rowc);
    hipLaunchKernelGGL(softmax_O_kernel, dim3(32), dim3(256), 0, stream, O, Om);

    void* args[] = { (void*)&Tm, (void*)&rowc, (void*)&Om, (void*)&syms,
                     (void*)&vwpart, (void*)&ready, (void*)&out };
    hipLaunchCooperativeKernel((const void*)scan_kernel, dim3(NJB * NPART), dim3(256),
                               args, 0, stream);
}